// Round 9
// baseline (194.906 us; speedup 1.0000x reference)
//
#include <hip/hip_runtime.h>
#include <cmath>

#define IMG_H 4096
#define IMG_W 4096
#define GX 8
#define GY 64
#define TCOLS 512            /* output cols per block (256 thr x 2) */
#define R 64                 /* output rows per block */
#define NITER (R + 10)       /* 74 h-rows per strip */
#define SWORDS 528           /* staged words per img-row: [c0-8, c0+520) */
#define NF4 132              /* float4 slots per img per row */
#define NSLOT (2*NF4)        /* 264 */

struct GW { float w[11]; };

__device__ __forceinline__ int clampi(int v, int lo, int hi) {
  return v < lo ? lo : (v > hi ? hi : v);
}

// Round-3 skeleton (measured best: 106 us tile) + 4-channel algebra ONLY.
// Lessons enforced:
//  - TAP-centric h-conv with flat per-tap product temps. Element-centric
//    restructure regressed twice (R5 132us, R8 131us vs R3 106us): compiler
//    schedules the shared-product chains badly, VALUBusy dropped to 36%.
//  - 4 channels: SSIM needs only sigma1^2+sigma2^2, so convolve
//    c2=G*(x^2+y^2), c3=G*(xy). Ring 110->88 VGPRs, -15% VALU (R8 verified
//    the VALU-time cut: 55->47us).
//  - LDS broadcast staging (R6: direct-global = 2x loss).
//  - Per-row barrier (R7: 4-row amortization regressed).
//  - launch_bounds min-wave arg stays 2 (R4: arg=4 -> 64-VGPR cap, ring
//    spilled, 983MB scratch, 5x slowdown).
__global__ __launch_bounds__(256, 2) void ssim_sweep_kernel(
    const float* __restrict__ img1, const float* __restrict__ img2,
    float* __restrict__ partial, GW gw) {
  __shared__ __align__(16) float sbuf[2][2][SWORDS];

  const int tid  = threadIdx.x;
  const int bx = blockIdx.x, by = blockIdx.y;
  const int c0   = bx * TCOLS;
  const int row0 = by * R;
  const bool edge = (bx == 0) || (bx == GX - 1);

  const int  j0   = tid;                 // staging slot 0..255
  const bool has2 = (tid < NSLOT - 256); // 8 threads take a 2nd slot
  const int  j1   = tid + 256;

  auto load_slot = [&](int j, int gr) -> float4 {
    const float* img = (j < NF4) ? img1 : img2;
    int wo = ((j < NF4) ? j : j - NF4) * 4;
    long rowbase = (long)gr * IMG_W;
    int gc = c0 - 8 + wo;
    if (!edge) {
      return *reinterpret_cast<const float4*>(img + rowbase + gc);
    } else {
      float4 v;
      v.x = img[rowbase + clampi(gc + 0, 0, IMG_W - 1)];
      v.y = img[rowbase + clampi(gc + 1, 0, IMG_W - 1)];
      v.z = img[rowbase + clampi(gc + 2, 0, IMG_W - 1)];
      v.w = img[rowbase + clampi(gc + 3, 0, IMG_W - 1)];
      return v;
    }
  };
  auto store_slot = [&](int buf, int j, float4 v) {
    int im = (j < NF4) ? 0 : 1;
    int wo = ((j < NF4) ? j : j - NF4) * 4;
    *reinterpret_cast<float4*>(&sbuf[buf][im][wo]) = v;
  };

  // ---- prologue: stage h-row 0 into buffer 0 ----
  {
    int gr = clampi(row0 - 5, 0, IMG_H - 1);
    float4 v0 = load_slot(j0, gr);
    store_slot(0, j0, v0);
    if (has2) { float4 v1 = load_slot(j1, gr); store_slot(0, j1, v1); }
  }

  // ring: 4 channels {mu1, mu2, E[x^2+y^2], E[xy]} x 11 slots x 2 cols
  float acc[4][11][2];
  #pragma unroll
  for (int ch = 0; ch < 4; ++ch)
    #pragma unroll
    for (int s = 0; s < 11; ++s) { acc[ch][s][0] = 0.f; acc[ch][s][1] = 0.f; }

  float sum = 0.f;
  const float C1 = 6.5025f, C2 = 58.5225f;
  const int base = 2 * tid + 2;   // first staged word of this thread's window

  for (int g = 0; g < 7; ++g) {
    #pragma unroll
    for (int p = 0; p < 11; ++p) {
      const int i = g * 11 + p;
      if (i < NITER) {
        __syncthreads();   // iter i-1 writes of buf[i&1] visible

        // prefetch next input row (global -> regs), hidden under compute
        float4 pre0, pre1;
        const bool pf = (i + 1 < NITER);
        if (pf) {
          int gr = clampi(row0 - 5 + i + 1, 0, IMG_H - 1);
          pre0 = load_slot(j0, gr);
          if (has2) pre1 = load_slot(j1, gr);
        }

        const int cur = i & 1;
        // window: staged words [2tid+2, 2tid+16); used: [1..12]
        float wa[14], wb[14];
        #pragma unroll
        for (int m = 0; m < 7; ++m) {
          float2 fa = *reinterpret_cast<const float2*>(&sbuf[cur][0][base + 2 * m]);
          float2 fb = *reinterpret_cast<const float2*>(&sbuf[cur][1][base + 2 * m]);
          wa[2 * m] = fa.x; wa[2 * m + 1] = fa.y;
          wb[2 * m] = fb.x; wb[2 * m + 1] = fb.y;
        }

        // reset ring slot that starts accumulating a new output this iter
        {
          const int rs = (p + 5) % 11;
          #pragma unroll
          for (int ch = 0; ch < 4; ++ch) { acc[ch][rs][0] = 0.f; acc[ch][rs][1] = 0.f; }
        }

        // fused 4-channel horizontal conv, TAP-centric, 2 cols
        float h[4][2];
        #pragma unroll
        for (int ch = 0; ch < 4; ++ch) { h[ch][0] = 0.f; h[ch][1] = 0.f; }
        #pragma unroll
        for (int j = 0; j < 11; ++j) {
          const float wj = gw.w[j];
          float a1 = wa[j + 1], a2 = wa[j + 2];
          float b1 = wb[j + 1], b2 = wb[j + 2];
          float sq1 = fmaf(b1, b1, a1 * a1), sq2 = fmaf(b2, b2, a2 * a2);
          float ab1 = a1 * b1,               ab2 = a2 * b2;
          h[0][0] = fmaf(wj, a1,  h[0][0]); h[0][1] = fmaf(wj, a2,  h[0][1]);
          h[1][0] = fmaf(wj, b1,  h[1][0]); h[1][1] = fmaf(wj, b2,  h[1][1]);
          h[2][0] = fmaf(wj, sq1, h[2][0]); h[2][1] = fmaf(wj, sq2, h[2][1]);
          h[3][0] = fmaf(wj, ab1, h[3][0]); h[3][1] = fmaf(wj, ab2, h[3][1]);
        }

        // scatter h-row into the 11 pending output rows (static slots)
        #pragma unroll
        for (int d = -5; d <= 5; ++d) {
          const int s = (p + d + 11) % 11;
          const float wd = gw.w[5 - d];
          #pragma unroll
          for (int ch = 0; ch < 4; ++ch) {
            acc[ch][s][0] = fmaf(wd, h[ch][0], acc[ch][s][0]);
            acc[ch][s][1] = fmaf(wd, h[ch][1], acc[ch][s][1]);
          }
        }

        // output row (i-10) complete in slot (p+6)%11 -> SSIM + sum
        if (i >= 10) {
          const int cs = (p + 6) % 11;
          #pragma unroll
          for (int x = 0; x < 2; ++x) {
            float mu1 = acc[0][cs][x], mu2 = acc[1][cs][x];
            float s2  = acc[2][cs][x], s3  = acc[3][cs][x];
            float mu1s = mu1 * mu1, mu2s = mu2 * mu2, m12 = mu1 * mu2;
            float num = (2.f * m12 + C1) * (2.f * (s3 - m12) + C2);
            float den = (mu1s + mu2s + C1) * ((s2 - mu1s - mu2s) + C2);
            sum += num * __builtin_amdgcn_rcpf(den);
          }
        }

        // commit prefetched row to the other buffer
        if (pf) {
          store_slot((i + 1) & 1, j0, pre0);
          if (has2) store_slot((i + 1) & 1, j1, pre1);
        }
      }
    }
  }

  // ---- block reduction ----
  #pragma unroll
  for (int off = 32; off > 0; off >>= 1) sum += __shfl_down(sum, off);
  __shared__ float wsum[4];
  if ((tid & 63) == 0) wsum[tid >> 6] = sum;
  __syncthreads();
  if (tid == 0)
    partial[by * GX + bx] = wsum[0] + wsum[1] + wsum[2] + wsum[3];
}

__global__ __launch_bounds__(256) void ssim_reduce_kernel(
    const float* __restrict__ partial, float* __restrict__ out) {
  int tid = threadIdx.x;
  double s = (double)partial[tid] + (double)partial[tid + 256];  // 512 partials
  #pragma unroll
  for (int off = 32; off > 0; off >>= 1) s += __shfl_down(s, off);
  __shared__ double ws[4];
  if ((tid & 63) == 0) ws[tid >> 6] = s;
  __syncthreads();
  if (tid == 0)
    out[0] = (float)((ws[0] + ws[1] + ws[2] + ws[3]) /
                     ((double)IMG_H * (double)IMG_W));
}

extern "C" void kernel_launch(void* const* d_in, const int* in_sizes, int n_in,
                              void* d_out, int out_size, void* d_ws, size_t ws_size,
                              hipStream_t stream) {
  const float* img1 = (const float*)d_in[0];
  const float* img2 = (const float*)d_in[1];
  float* partial = (float*)d_ws;
  float* out = (float*)d_out;

  GW gw;
  double g[11], s = 0.0;
  for (int i = 0; i < 11; ++i) {
    double x = i - 5.0;
    g[i] = exp(-(x * x) / (2.0 * 1.5 * 1.5));
    s += g[i];
  }
  for (int i = 0; i < 11; ++i) gw.w[i] = (float)(g[i] / s);

  dim3 grid(GX, GY);
  ssim_sweep_kernel<<<grid, 256, 0, stream>>>(img1, img2, partial, gw);
  ssim_reduce_kernel<<<1, 256, 0, stream>>>(partial, out);
}